// Round 8
// baseline (6586.893 us; speedup 1.0000x reference)
//
#include <hip/hip_runtime.h>
#include <math.h>

#define NB 16384   // batch
#define SROWS 32   // rows per SDE workgroup (72 KB LDS -> 2 WGs/CU)

__device__ __forceinline__ float swishf(float x) {
    return __fdividef(x, 1.0f + __expf(-x));
}

__device__ __forceinline__ float softplusf(float x) {
    return fmaxf(x, 0.0f) + log1pf(__expf(-fabsf(x)));
}

// ---------------------------------------------------------------------------
// Encoder GEMM: C[M,N] = act(A[M,K] @ W[K,N] + bias[N] (+ res[M,N]))
// 128x64 tile, BK=16, 256 threads, 8x4 microtile. (unchanged)
// ---------------------------------------------------------------------------
__global__ __launch_bounds__(256)
void gemm_bias_act(const float* __restrict__ A, const float* __restrict__ W,
                   const float* __restrict__ bias, const float* __restrict__ res,
                   float* __restrict__ C, int M, int N, int K, int act)
{
    __shared__ float As[16][132];  // [k][m], 128 rows + pad
    __shared__ float Bs[16][68];   // [k][n], padded

    const int tid  = threadIdx.x;
    const int row0 = blockIdx.y * 128;
    const int col0 = blockIdx.x * 64;
    const int tx = tid & 15;
    const int ty = tid >> 4;

    const int lm = tid >> 2;          // 0..63 : A row within panel
    const int lk = (tid & 3) << 2;    // 0,4,8,12 : A k quad
    const int bk = tid >> 4;          // 0..15 : W k row
    const int bn = (tid & 15) << 2;   // 0..60 : W col quad

    float acc[8][4] = {};

    for (int k0 = 0; k0 < K; k0 += 16) {
        const float4 av0 = *(const float4*)&A[(size_t)(row0 + lm) * K + k0 + lk];
        const float4 av1 = *(const float4*)&A[(size_t)(row0 + 64 + lm) * K + k0 + lk];
        const float4 bv  = *(const float4*)&W[(size_t)(k0 + bk) * N + col0 + bn];
        As[lk + 0][lm] = av0.x;
        As[lk + 1][lm] = av0.y;
        As[lk + 2][lm] = av0.z;
        As[lk + 3][lm] = av0.w;
        As[lk + 0][64 + lm] = av1.x;
        As[lk + 1][64 + lm] = av1.y;
        As[lk + 2][64 + lm] = av1.z;
        As[lk + 3][64 + lm] = av1.w;
        *(float4*)&Bs[bk][bn] = bv;
        __syncthreads();
        #pragma unroll
        for (int k = 0; k < 16; ++k) {
            const float4 a0 = *(const float4*)&As[k][ty << 2];
            const float4 a1 = *(const float4*)&As[k][64 + (ty << 2)];
            const float4 b  = *(const float4*)&Bs[k][tx << 2];
            acc[0][0] += a0.x*b.x; acc[0][1] += a0.x*b.y; acc[0][2] += a0.x*b.z; acc[0][3] += a0.x*b.w;
            acc[1][0] += a0.y*b.x; acc[1][1] += a0.y*b.y; acc[1][2] += a0.y*b.z; acc[1][3] += a0.y*b.w;
            acc[2][0] += a0.z*b.x; acc[2][1] += a0.z*b.y; acc[2][2] += a0.z*b.z; acc[2][3] += a0.z*b.w;
            acc[3][0] += a0.w*b.x; acc[3][1] += a0.w*b.y; acc[3][2] += a0.w*b.z; acc[3][3] += a0.w*b.w;
            acc[4][0] += a1.x*b.x; acc[4][1] += a1.x*b.y; acc[4][2] += a1.x*b.z; acc[4][3] += a1.x*b.w;
            acc[5][0] += a1.y*b.x; acc[5][1] += a1.y*b.y; acc[5][2] += a1.y*b.z; acc[5][3] += a1.y*b.w;
            acc[6][0] += a1.z*b.x; acc[6][1] += a1.z*b.y; acc[6][2] += a1.z*b.z; acc[6][3] += a1.z*b.w;
            acc[7][0] += a1.w*b.x; acc[7][1] += a1.w*b.y; acc[7][2] += a1.w*b.z; acc[7][3] += a1.w*b.w;
        }
        __syncthreads();
    }

    #pragma unroll
    for (int i = 0; i < 8; ++i) {
        const int r = row0 + ((i < 4) ? 0 : 64) + (ty << 2) + (i & 3);
        #pragma unroll
        for (int j = 0; j < 4; ++j) {
            const int c = col0 + (tx << 2) + j;
            float v = acc[i][j] + bias[c];
            if (res) v += res[(size_t)r * N + c];
            if (act) v = swishf(v);
            C[(size_t)r * N + c] = v;
        }
    }
}

// ---------------------------------------------------------------------------
// mu / s split: lp[NB,128] -> mu = lp[:, :64], s = exp(0.5*lp[:, 64:])
// ---------------------------------------------------------------------------
__global__ __launch_bounds__(256)
void mu_s_kernel(const float* __restrict__ lp, float* __restrict__ mu,
                 float* __restrict__ s)
{
    const int idx = blockIdx.x * 256 + threadIdx.x;   // < NB*64
    const int row = idx >> 6;
    const int c   = idx & 63;
    mu[idx] = lp[(row << 7) + c];
    s[idx]  = expf(0.5f * lp[(row << 7) + 64 + c]);
}

// ---------------------------------------------------------------------------
// SDE phase helpers.  All LDS activation reads are wave-uniform broadcasts
// (or 2-way splits, free per bank rules).  One v_fmac_f32 per MAC.
// ---------------------------------------------------------------------------

// H1/G1: out[r][c4+j] = swish(bj[j] + sum_k z[r][k]*W[1+k][c4+j]), j=0..3,
// rows rbase..rbase+R-1.  1 b128 LDS read per 16 FMAs.
template<int R>
__device__ __forceinline__ void phase65_4col(
    const float (*zb)[64], float (*out)[256],
    const float* __restrict__ W, float4 bj, int c4, int rbase)
{
    float a0[R], a1[R], a2[R], a3[R];
    #pragma unroll
    for (int r = 0; r < R; ++r) { a0[r] = bj.x; a1[r] = bj.y; a2[r] = bj.z; a3[r] = bj.w; }

    #pragma unroll 1
    for (int ch = 0; ch < 4; ++ch) {          // K chunks of 16 (K=64)
        float4 w[16];
        #pragma unroll
        for (int k = 0; k < 16; ++k)
            w[k] = *(const float4*)&W[(size_t)(ch * 16 + k + 1) * 256 + c4];
        #pragma unroll
        for (int r = 0; r < R; ++r) {
            #pragma unroll
            for (int q = 0; q < 4; ++q) {
                const float4 z4 = *(const float4*)&zb[rbase + r][ch * 16 + (q << 2)];
                const int k0 = q << 2;
                a0[r] += z4.x*w[k0+0].x; a0[r] += z4.y*w[k0+1].x; a0[r] += z4.z*w[k0+2].x; a0[r] += z4.w*w[k0+3].x;
                a1[r] += z4.x*w[k0+0].y; a1[r] += z4.y*w[k0+1].y; a1[r] += z4.z*w[k0+2].y; a1[r] += z4.w*w[k0+3].y;
                a2[r] += z4.x*w[k0+0].z; a2[r] += z4.y*w[k0+1].z; a2[r] += z4.z*w[k0+2].z; a2[r] += z4.w*w[k0+3].z;
                a3[r] += z4.x*w[k0+0].w; a3[r] += z4.y*w[k0+1].w; a3[r] += z4.z*w[k0+2].w; a3[r] += z4.w*w[k0+3].w;
            }
        }
    }
    #pragma unroll
    for (int r = 0; r < R; ++r) {
        float4 o;
        o.x = swishf(a0[r]); o.y = swishf(a1[r]); o.z = swishf(a2[r]); o.w = swishf(a3[r]);
        *(float4*)&out[rbase + r][c4] = o;
    }
}

// H2: K=256, 4 adjacent output cols (c4..c4+3), R rows.  Acc in VGPRs.
// 1 b128 LDS read per 16 FMAs.  K chunks of 8, unroll 1: live set =
// 32 weight VGPRs + 32 accumulators.
template<int R>
__device__ __forceinline__ void accum4_k256(
    const float (*src)[256], const float* __restrict__ W,
    int c4, int rbase,
    float (&a0)[R], float (&a1)[R], float (&a2)[R], float (&a3)[R])
{
    #pragma unroll 1
    for (int ch = 0; ch < 32; ++ch) {         // K chunks of 8 (K=256)
        float4 w[8];
        #pragma unroll
        for (int k = 0; k < 8; ++k)
            w[k] = *(const float4*)&W[(size_t)(ch * 8 + k) * 256 + c4];
        #pragma unroll
        for (int r = 0; r < R; ++r) {
            #pragma unroll
            for (int q = 0; q < 2; ++q) {
                const float4 h4 = *(const float4*)&src[rbase + r][ch * 8 + (q << 2)];
                const int k0 = q << 2;
                a0[r] += h4.x*w[k0+0].x; a0[r] += h4.y*w[k0+1].x; a0[r] += h4.z*w[k0+2].x; a0[r] += h4.w*w[k0+3].x;
                a1[r] += h4.x*w[k0+0].y; a1[r] += h4.y*w[k0+1].y; a1[r] += h4.z*w[k0+2].y; a1[r] += h4.w*w[k0+3].y;
                a2[r] += h4.x*w[k0+0].z; a2[r] += h4.y*w[k0+1].z; a2[r] += h4.z*w[k0+2].z; a2[r] += h4.w*w[k0+3].z;
                a3[r] += h4.x*w[k0+0].w; a3[r] += h4.y*w[k0+1].w; a3[r] += h4.z*w[k0+2].w; a3[r] += h4.w*w[k0+3].w;
            }
        }
    }
}

// D3/G2: K=256 accumulate, 2 adjacent output cols {c2, c2+1}, R rows.
// 1 b128 LDS read per 8 FMAs.
template<int R>
__device__ __forceinline__ void accum2(
    const float (*src)[256], const float* __restrict__ W, int ldw,
    int c2, int rbase, float (&ax)[R], float (&ay)[R])
{
    #pragma unroll 2
    for (int ch = 0; ch < 16; ++ch) {         // K chunks of 16 (K=256)
        float2 w[16];
        #pragma unroll
        for (int k = 0; k < 16; ++k)
            w[k] = *(const float2*)&W[(size_t)(ch * 16 + k) * ldw + c2];
        #pragma unroll
        for (int r = 0; r < R; ++r) {
            #pragma unroll
            for (int q = 0; q < 4; ++q) {
                const float4 h4 = *(const float4*)&src[rbase + r][ch * 16 + (q << 2)];
                const int k0 = q << 2;
                ax[r] += h4.x*w[k0+0].x; ax[r] += h4.y*w[k0+1].x; ax[r] += h4.z*w[k0+2].x; ax[r] += h4.w*w[k0+3].x;
                ay[r] += h4.x*w[k0+0].y; ay[r] += h4.y*w[k0+1].y; ay[r] += h4.z*w[k0+2].y; ay[r] += h4.w*w[k0+3].y;
            }
        }
    }
}

// ---------------------------------------------------------------------------
// Persistent SDE kernel: all 63 steps in one launch, z kept in LDS.
// 512 WGs x 256 threads, 32 rows each; LDS 72 KB -> 2 WGs/CU (8 waves/CU).
// amdgpu_waves_per_eu(2,2): LDS caps us at 2 waves/SIMD anyway, so pin the
// allocator's occupancy target there -> VGPR budget 256, not the 128 wall
// it spilled against in rounds 4/6 (1.8 GB scratch traffic at VGPR==128).
// Thread->work mappings (all wave-uniform or 2-way on LDS row addresses):
//   H1/G1/H2 : thread = (rowband tid>>6 [8 rows], colquad 4*(tid&63))
//   D3/G2    : thread = (rowgrp tid>>5 [4 rows],  colpair 2*(tid&31))
// ---------------------------------------------------------------------------
__global__ __launch_bounds__(256)
__attribute__((amdgpu_waves_per_eu(2, 2)))
void sde_kernel(const float* __restrict__ ts, const float* __restrict__ noise,
                const float* __restrict__ Wd1, const float* __restrict__ bd1,
                const float* __restrict__ Wd2, const float* __restrict__ bd2,
                const float* __restrict__ Wd3, const float* __restrict__ bd3,
                const float* __restrict__ Wg1, const float* __restrict__ bg1,
                const float* __restrict__ Wg2, const float* __restrict__ bg2,
                float* __restrict__ zpath)
{
    __shared__ float zbuf[SROWS][64];    //  8 KB : persistent z state
    __shared__ float bufA[SROWS][256];   // 32 KB : h1, then g1
    __shared__ float bufB[SROWS][256];   // 32 KB : h2

    const int tid  = threadIdx.x;
    const int row0 = blockIdx.x * SROWS;

    const int c4 = (tid & 63) << 2;      // H1/G1/H2 col quad
    const int r4 = (tid >> 6) << 3;      // H1/G1/H2 row base (8 rows)
    const int cq = (tid & 31) << 1;      // D3/G2 col pair
    const int r8 = (tid >> 5) << 2;      // D3/G2 row base (4 rows)

    // biases / t-row weights held in registers for the whole kernel
    const float4 bd1v = *(const float4*)&bd1[c4];
    const float4 w0d  = *(const float4*)&Wd1[c4];   // Wd1 row k=0 (t coeff)
    const float4 bg1v = *(const float4*)&bg1[c4];
    const float4 w0g  = *(const float4*)&Wg1[c4];
    const float4 bd2v = *(const float4*)&bd2[c4];
    const float2 bd3v = *(const float2*)&bd3[cq];
    const float2 bg2v = *(const float2*)&bg2[cq];

    // load z0 from z_path[0]
    #pragma unroll
    for (int i = 0; i < (SROWS * 64 / 4) / 256; ++i) {
        const int f = tid + i * 256;      // float4 index
        const int e = f << 2;             // float index
        const float4 v = *(const float4*)&zpath[(size_t)row0 * 64 + e];
        *(float4*)&zbuf[e >> 6][e & 63] = v;
    }
    __syncthreads();

    for (int step = 0; step < 63; ++step) {
        const float t  = ts[step];
        const float dt = ts[step + 1] - t;
        const float sq = sqrtf(dt);

        // H1 = swish([t,z] @ Wd1 + bd1) -> bufA
        float4 bj;
        bj.x = bd1v.x + t * w0d.x; bj.y = bd1v.y + t * w0d.y;
        bj.z = bd1v.z + t * w0d.z; bj.w = bd1v.w + t * w0d.w;
        phase65_4col<8>(zbuf, bufA, Wd1, bj, c4, r4);
        __syncthreads();

        // H2 = swish(H1 @ Wd2 + bd2) -> bufB   (C=4, acc in VGPRs)
        {
            float a0[8], a1[8], a2[8], a3[8];
            #pragma unroll
            for (int r = 0; r < 8; ++r) {
                a0[r] = bd2v.x; a1[r] = bd2v.y; a2[r] = bd2v.z; a3[r] = bd2v.w;
            }
            accum4_k256<8>(bufA, Wd2, c4, r4, a0, a1, a2, a3);
            #pragma unroll
            for (int r = 0; r < 8; ++r) {
                float4 o;
                o.x = swishf(a0[r]); o.y = swishf(a1[r]);
                o.z = swishf(a2[r]); o.w = swishf(a3[r]);
                *(float4*)&bufB[r4 + r][c4] = o;
            }
        }
        __syncthreads();   // bufA consumed; bufB ready

        // G1 = swish([t,z] @ Wg1 + bg1) -> bufA (overwrites h1)
        bj.x = bg1v.x + t * w0g.x; bj.y = bg1v.y + t * w0g.y;
        bj.z = bg1v.z + t * w0g.z; bj.w = bg1v.w + t * w0g.w;
        phase65_4col<8>(zbuf, bufA, Wg1, bj, c4, r4);
        __syncthreads();   // bufA(g1) ready

        // D = H2 @ Wd3 + bd3 ; G = softplus(G1 @ Wg2 + bg2) ; z update
        {
            float dx[4], dy[4], gx[4], gy[4];
            #pragma unroll
            for (int r = 0; r < 4; ++r) {
                dx[r] = bd3v.x; dy[r] = bd3v.y;
                gx[r] = bg2v.x; gy[r] = bg2v.y;
            }
            accum2<4>(bufB, Wd3, 64, cq, r8, dx, dy);
            accum2<4>(bufA, Wg2, 64, cq, r8, gx, gy);

            const size_t nbase = ((size_t)step * NB + row0) * 64;
            float* zo = zpath + ((size_t)(step + 1) * NB + row0) * 64;
            #pragma unroll
            for (int r = 0; r < 4; ++r) {
                const int rr = r8 + r;
                const float2 nz = *(const float2*)&noise[nbase + (size_t)rr * 64 + cq];
                const float2 zc = *(const float2*)&zbuf[rr][cq];
                const float zx = zc.x + dx[r] * dt + softplusf(gx[r]) * sq * nz.x;
                const float zy = zc.y + dy[r] * dt + softplusf(gy[r]) * sq * nz.y;
                float2 o; o.x = zx; o.y = zy;
                *(float2*)&zbuf[rr][cq] = o;
                *(float2*)&zo[(size_t)rr * 64 + cq] = o;
            }
        }
        __syncthreads();   // zbuf ready for next step
    }
}

// ---------------------------------------------------------------------------
extern "C" void kernel_launch(void* const* d_in, const int* in_sizes, int n_in,
                              void* d_out, int out_size, void* d_ws, size_t ws_size,
                              hipStream_t stream)
{
    const float* x      = (const float*)d_in[0];
    const float* ts     = (const float*)d_in[1];
    const float* noise  = (const float*)d_in[2];
    const float* W_in   = (const float*)d_in[3];
    const float* b_in   = (const float*)d_in[4];
    const float* Wb1    = (const float*)d_in[5];
    const float* bb1    = (const float*)d_in[6];
    const float* Wb2    = (const float*)d_in[7];
    const float* bb2    = (const float*)d_in[8];
    const float* W_fo   = (const float*)d_in[9];
    const float* b_fo   = (const float*)d_in[10];
    const float* W_lat  = (const float*)d_in[11];
    const float* b_lat  = (const float*)d_in[12];
    const float* W_init = (const float*)d_in[13];
    const float* b_init = (const float*)d_in[14];
    const float* Wd1    = (const float*)d_in[15];
    const float* bd1    = (const float*)d_in[16];
    const float* Wd2    = (const float*)d_in[17];
    const float* bd2    = (const float*)d_in[18];
    const float* Wd3    = (const float*)d_in[19];
    const float* bd3    = (const float*)d_in[20];
    const float* Wg1    = (const float*)d_in[21];
    const float* bg1    = (const float*)d_in[22];
    const float* Wg2    = (const float*)d_in[23];
    const float* bg2    = (const float*)d_in[24];

    float* out   = (float*)d_out;
    float* mu_o  = out;                              // [NB,64]
    float* s_o   = out + (size_t)NB * 64;            // [NB,64]
    float* zpath = out + (size_t)2 * NB * 64;        // [64,NB,64]

    float* bufH = (float*)d_ws;                      // [NB,256]
    float* bufT = bufH + (size_t)NB * 256;           // [NB,256]
    // total ws use: 32 MB

    const dim3 blk(256);
    auto g = [&](const float* A, const float* W, const float* b,
                 const float* res, float* C, int N, int act) {
        dim3 grd(N / 64, NB / 128);
        gemm_bias_act<<<grd, blk, 0, stream>>>(A, W, b, res, C, NB, N, 256, act);
    };

    // encoder
    g(x, W_in, b_in, nullptr, bufH, 256, 1);                       // h = swish(x@W_in+b)
    for (int i = 0; i < 3; ++i) {
        g(bufH, Wb1 + (size_t)i * 65536, bb1 + i * 256, nullptr, bufT, 256, 1);
        g(bufT, Wb2 + (size_t)i * 65536, bb2 + i * 256, bufH, bufH, 256, 0);  // residual, in-place ok
    }
    g(bufH, W_fo, b_fo, nullptr, bufT, 256, 0);                    // features -> bufT
    g(bufT, W_lat, b_lat, nullptr, bufH, 128, 0);                  // latent_params -> bufH
    mu_s_kernel<<<dim3(NB * 64 / 256), blk, 0, stream>>>(bufH, mu_o, s_o);
    g(bufT, W_init, b_init, nullptr, zpath, 64, 0);                // z0 -> z_path[0]

    // SDE: 63 steps, persistent
    sde_kernel<<<dim3(NB / SROWS), blk, 0, stream>>>(
        ts, noise, Wd1, bd1, Wd2, bd2, Wd3, bd3, Wg1, bg1, Wg2, bg2, zpath);
}

// Round 12
// 6018.242 us; speedup vs baseline: 1.0945x; 1.0945x over previous
//
#include <hip/hip_runtime.h>
#include <math.h>

#define NB 16384   // batch
#define SROWS 32   // rows per SDE workgroup (72 KB LDS -> 2 WGs/CU)

__device__ __forceinline__ float swishf(float x) {
    return __fdividef(x, 1.0f + __expf(-x));
}

__device__ __forceinline__ float softplusf(float x) {
    return fmaxf(x, 0.0f) + log1pf(__expf(-fabsf(x)));
}

// ---------------------------------------------------------------------------
// Encoder GEMM: C[M,N] = act(A[M,K] @ W[K,N] + bias[N] (+ res[M,N]))
// 128x64 tile, BK=16, 256 threads, 8x4 microtile. (unchanged)
// ---------------------------------------------------------------------------
__global__ __launch_bounds__(256)
void gemm_bias_act(const float* __restrict__ A, const float* __restrict__ W,
                   const float* __restrict__ bias, const float* __restrict__ res,
                   float* __restrict__ C, int M, int N, int K, int act)
{
    __shared__ float As[16][132];  // [k][m], 128 rows + pad
    __shared__ float Bs[16][68];   // [k][n], padded

    const int tid  = threadIdx.x;
    const int row0 = blockIdx.y * 128;
    const int col0 = blockIdx.x * 64;
    const int tx = tid & 15;
    const int ty = tid >> 4;

    const int lm = tid >> 2;          // 0..63 : A row within panel
    const int lk = (tid & 3) << 2;    // 0,4,8,12 : A k quad
    const int bk = tid >> 4;          // 0..15 : W k row
    const int bn = (tid & 15) << 2;   // 0..60 : W col quad

    float acc[8][4] = {};

    for (int k0 = 0; k0 < K; k0 += 16) {
        const float4 av0 = *(const float4*)&A[(size_t)(row0 + lm) * K + k0 + lk];
        const float4 av1 = *(const float4*)&A[(size_t)(row0 + 64 + lm) * K + k0 + lk];
        const float4 bv  = *(const float4*)&W[(size_t)(k0 + bk) * N + col0 + bn];
        As[lk + 0][lm] = av0.x;
        As[lk + 1][lm] = av0.y;
        As[lk + 2][lm] = av0.z;
        As[lk + 3][lm] = av0.w;
        As[lk + 0][64 + lm] = av1.x;
        As[lk + 1][64 + lm] = av1.y;
        As[lk + 2][64 + lm] = av1.z;
        As[lk + 3][64 + lm] = av1.w;
        *(float4*)&Bs[bk][bn] = bv;
        __syncthreads();
        #pragma unroll
        for (int k = 0; k < 16; ++k) {
            const float4 a0 = *(const float4*)&As[k][ty << 2];
            const float4 a1 = *(const float4*)&As[k][64 + (ty << 2)];
            const float4 b  = *(const float4*)&Bs[k][tx << 2];
            acc[0][0] += a0.x*b.x; acc[0][1] += a0.x*b.y; acc[0][2] += a0.x*b.z; acc[0][3] += a0.x*b.w;
            acc[1][0] += a0.y*b.x; acc[1][1] += a0.y*b.y; acc[1][2] += a0.y*b.z; acc[1][3] += a0.y*b.w;
            acc[2][0] += a0.z*b.x; acc[2][1] += a0.z*b.y; acc[2][2] += a0.z*b.z; acc[2][3] += a0.z*b.w;
            acc[3][0] += a0.w*b.x; acc[3][1] += a0.w*b.y; acc[3][2] += a0.w*b.z; acc[3][3] += a0.w*b.w;
            acc[4][0] += a1.x*b.x; acc[4][1] += a1.x*b.y; acc[4][2] += a1.x*b.z; acc[4][3] += a1.x*b.w;
            acc[5][0] += a1.y*b.x; acc[5][1] += a1.y*b.y; acc[5][2] += a1.y*b.z; acc[5][3] += a1.y*b.w;
            acc[6][0] += a1.z*b.x; acc[6][1] += a1.z*b.y; acc[6][2] += a1.z*b.z; acc[6][3] += a1.z*b.w;
            acc[7][0] += a1.w*b.x; acc[7][1] += a1.w*b.y; acc[7][2] += a1.w*b.z; acc[7][3] += a1.w*b.w;
        }
        __syncthreads();
    }

    #pragma unroll
    for (int i = 0; i < 8; ++i) {
        const int r = row0 + ((i < 4) ? 0 : 64) + (ty << 2) + (i & 3);
        #pragma unroll
        for (int j = 0; j < 4; ++j) {
            const int c = col0 + (tx << 2) + j;
            float v = acc[i][j] + bias[c];
            if (res) v += res[(size_t)r * N + c];
            if (act) v = swishf(v);
            C[(size_t)r * N + c] = v;
        }
    }
}

// ---------------------------------------------------------------------------
// mu / s split: lp[NB,128] -> mu = lp[:, :64], s = exp(0.5*lp[:, 64:])
// ---------------------------------------------------------------------------
__global__ __launch_bounds__(256)
void mu_s_kernel(const float* __restrict__ lp, float* __restrict__ mu,
                 float* __restrict__ s)
{
    const int idx = blockIdx.x * 256 + threadIdx.x;   // < NB*64
    const int row = idx >> 6;
    const int c   = idx & 63;
    mu[idx] = lp[(row << 7) + c];
    s[idx]  = expf(0.5f * lp[(row << 7) + 64 + c]);
}

// ---------------------------------------------------------------------------
// SDE phase helpers.  All LDS activation reads are wave-uniform broadcasts
// (or 2-way splits, free per bank rules).  One v_fmac_f32 per MAC.
// Register discipline (hard-won, r2 vs r4/r6/r8 evidence):
//   - float2-weight accum (accum2) with unroll 2 compiles clean (92 VGPR);
//   - float4-weight K256 accum (accum4) spilled (~1.1 GB scratch) in every
//     variant -> reverted.
//   - biases reloaded per phase, not held across the kernel.
// ---------------------------------------------------------------------------

// H1/G1: out[r][c4+j] = swish(b[j] + t*W0[j] + sum_k z[r][k]*W[1+k][c4+j]),
// j=0..3, rows rbase..rbase+R-1.  K chunks of 8 with unroll 2 so the
// scheduler pipelines next chunk's weight loads under current FMAs.
template<int R>
__device__ __forceinline__ void phase65_4col(
    const float (*zb)[64], float (*out)[256],
    const float* __restrict__ W, const float* __restrict__ bvec,
    float t, int c4, int rbase)
{
    const float4 b4  = *(const float4*)&bvec[c4];
    const float4 w04 = *(const float4*)&W[c4];   // k=0 row (t coefficient)
    float a0[R], a1[R], a2[R], a3[R];
    #pragma unroll
    for (int r = 0; r < R; ++r) {
        a0[r] = b4.x + t * w04.x; a1[r] = b4.y + t * w04.y;
        a2[r] = b4.z + t * w04.z; a3[r] = b4.w + t * w04.w;
    }

    #pragma unroll 2
    for (int ch = 0; ch < 8; ++ch) {          // K chunks of 8 (K=64)
        float4 w[8];
        #pragma unroll
        for (int k = 0; k < 8; ++k)
            w[k] = *(const float4*)&W[(size_t)(ch * 8 + k + 1) * 256 + c4];
        #pragma unroll
        for (int r = 0; r < R; ++r) {
            #pragma unroll
            for (int q = 0; q < 2; ++q) {
                const float4 z4 = *(const float4*)&zb[rbase + r][ch * 8 + (q << 2)];
                const int k0 = q << 2;
                a0[r] += z4.x*w[k0+0].x; a0[r] += z4.y*w[k0+1].x; a0[r] += z4.z*w[k0+2].x; a0[r] += z4.w*w[k0+3].x;
                a1[r] += z4.x*w[k0+0].y; a1[r] += z4.y*w[k0+1].y; a1[r] += z4.z*w[k0+2].y; a1[r] += z4.w*w[k0+3].y;
                a2[r] += z4.x*w[k0+0].z; a2[r] += z4.y*w[k0+1].z; a2[r] += z4.z*w[k0+2].z; a2[r] += z4.w*w[k0+3].z;
                a3[r] += z4.x*w[k0+0].w; a3[r] += z4.y*w[k0+1].w; a3[r] += z4.z*w[k0+2].w; a3[r] += z4.w*w[k0+3].w;
            }
        }
    }
    #pragma unroll
    for (int r = 0; r < R; ++r) {
        float4 o;
        o.x = swishf(a0[r]); o.y = swishf(a1[r]); o.z = swishf(a2[r]); o.w = swishf(a3[r]);
        *(float4*)&out[rbase + r][c4] = o;
    }
}

// K=256 accumulate, 2 adjacent output cols {c2, c2+1}, R rows from rbase.
// float2 weights, unroll 2 -> proven clean codegen + load pipelining (r2).
template<int R>
__device__ __forceinline__ void accum2(
    const float (*src)[256], const float* __restrict__ W, int ldw,
    int c2, int rbase, float (&ax)[R], float (&ay)[R])
{
    #pragma unroll 2
    for (int ch = 0; ch < 16; ++ch) {         // K chunks of 16 (K=256)
        float2 w[16];
        #pragma unroll
        for (int k = 0; k < 16; ++k)
            w[k] = *(const float2*)&W[(size_t)(ch * 16 + k) * ldw + c2];
        #pragma unroll
        for (int r = 0; r < R; ++r) {
            #pragma unroll
            for (int q = 0; q < 4; ++q) {
                const float4 h4 = *(const float4*)&src[rbase + r][ch * 16 + (q << 2)];
                const int k0 = q << 2;
                ax[r] += h4.x*w[k0+0].x; ax[r] += h4.y*w[k0+1].x; ax[r] += h4.z*w[k0+2].x; ax[r] += h4.w*w[k0+3].x;
                ay[r] += h4.x*w[k0+0].y; ay[r] += h4.y*w[k0+1].y; ay[r] += h4.z*w[k0+2].y; ay[r] += h4.w*w[k0+3].y;
            }
        }
    }
}

// ---------------------------------------------------------------------------
// Persistent SDE kernel: all 63 steps in one launch, z kept in LDS.
// 512 WGs x 256 threads, 32 rows each; LDS 72 KB -> 2 WGs/CU (8 waves/CU).
// Thread->work mappings (all wave-uniform or 2-way on LDS row addresses):
//   H1/G1 : thread = (rowband tid>>6 [8 rows],  colquad 4*(tid&63))
//   H2    : thread = (rowhalf tid>>7 [16 rows], colpair 2*(tid&127))
//   D3/G2 : thread = (rowgrp tid>>5 [4 rows],   colpair 2*(tid&31))
// ---------------------------------------------------------------------------
__global__ __launch_bounds__(256, 2)
void sde_kernel(const float* __restrict__ ts, const float* __restrict__ noise,
                const float* __restrict__ Wd1, const float* __restrict__ bd1,
                const float* __restrict__ Wd2, const float* __restrict__ bd2,
                const float* __restrict__ Wd3, const float* __restrict__ bd3,
                const float* __restrict__ Wg1, const float* __restrict__ bg1,
                const float* __restrict__ Wg2, const float* __restrict__ bg2,
                float* __restrict__ zpath)
{
    __shared__ float zbuf[SROWS][64];    //  8 KB : persistent z state
    __shared__ float bufA[SROWS][256];   // 32 KB : h1, then g1
    __shared__ float bufB[SROWS][256];   // 32 KB : h2

    const int tid  = threadIdx.x;
    const int row0 = blockIdx.x * SROWS;

    const int c4 = (tid & 63) << 2;      // H1/G1 col quad
    const int r4 = (tid >> 6) << 3;      // H1/G1 row base (8 rows)
    const int c2 = (tid & 127) << 1;     // H2 col pair
    const int r2 = (tid >> 7) << 4;      // H2 row base (16 rows)
    const int cq = (tid & 31) << 1;      // D3/G2 col pair
    const int r8 = (tid >> 5) << 2;      // D3/G2 row base (4 rows)

    // load z0 from z_path[0]
    #pragma unroll
    for (int i = 0; i < (SROWS * 64 / 4) / 256; ++i) {
        const int f = tid + i * 256;      // float4 index
        const int e = f << 2;             // float index
        const float4 v = *(const float4*)&zpath[(size_t)row0 * 64 + e];
        *(float4*)&zbuf[e >> 6][e & 63] = v;
    }
    __syncthreads();

    for (int step = 0; step < 63; ++step) {
        const float t  = ts[step];
        const float dt = ts[step + 1] - t;
        const float sq = sqrtf(dt);

        // H1 = swish([t,z] @ Wd1 + bd1) -> bufA
        phase65_4col<8>(zbuf, bufA, Wd1, bd1, t, c4, r4);
        __syncthreads();

        // H2 = swish(H1 @ Wd2 + bd2) -> bufB  (r2-proven accum2<16> shape)
        {
            const float2 b2 = *(const float2*)&bd2[c2];
            float ax[16], ay[16];
            #pragma unroll
            for (int r = 0; r < 16; ++r) { ax[r] = b2.x; ay[r] = b2.y; }
            accum2<16>(bufA, Wd2, 256, c2, r2, ax, ay);
            #pragma unroll
            for (int r = 0; r < 16; ++r) {
                float2 o; o.x = swishf(ax[r]); o.y = swishf(ay[r]);
                *(float2*)&bufB[r2 + r][c2] = o;
            }
        }
        __syncthreads();   // bufA consumed; bufB ready

        // G1 = swish([t,z] @ Wg1 + bg1) -> bufA (overwrites h1)
        phase65_4col<8>(zbuf, bufA, Wg1, bg1, t, c4, r4);
        __syncthreads();   // bufA(g1) ready

        // D = H2 @ Wd3 + bd3 ; G = softplus(G1 @ Wg2 + bg2) ; z update
        {
            const float2 b3 = *(const float2*)&bd3[cq];
            const float2 bg = *(const float2*)&bg2[cq];
            float dx[4], dy[4], gx[4], gy[4];
            #pragma unroll
            for (int r = 0; r < 4; ++r) {
                dx[r] = b3.x; dy[r] = b3.y;
                gx[r] = bg.x; gy[r] = bg.y;
            }
            accum2<4>(bufB, Wd3, 64, cq, r8, dx, dy);
            accum2<4>(bufA, Wg2, 64, cq, r8, gx, gy);

            const size_t nbase = ((size_t)step * NB + row0) * 64;
            float* zo = zpath + ((size_t)(step + 1) * NB + row0) * 64;
            #pragma unroll
            for (int r = 0; r < 4; ++r) {
                const int rr = r8 + r;
                const float2 nz = *(const float2*)&noise[nbase + (size_t)rr * 64 + cq];
                const float2 zc = *(const float2*)&zbuf[rr][cq];
                const float zx = zc.x + dx[r] * dt + softplusf(gx[r]) * sq * nz.x;
                const float zy = zc.y + dy[r] * dt + softplusf(gy[r]) * sq * nz.y;
                float2 o; o.x = zx; o.y = zy;
                *(float2*)&zbuf[rr][cq] = o;
                *(float2*)&zo[(size_t)rr * 64 + cq] = o;
            }
        }
        __syncthreads();   // zbuf ready for next step
    }
}

// ---------------------------------------------------------------------------
extern "C" void kernel_launch(void* const* d_in, const int* in_sizes, int n_in,
                              void* d_out, int out_size, void* d_ws, size_t ws_size,
                              hipStream_t stream)
{
    const float* x      = (const float*)d_in[0];
    const float* ts     = (const float*)d_in[1];
    const float* noise  = (const float*)d_in[2];
    const float* W_in   = (const float*)d_in[3];
    const float* b_in   = (const float*)d_in[4];
    const float* Wb1    = (const float*)d_in[5];
    const float* bb1    = (const float*)d_in[6];
    const float* Wb2    = (const float*)d_in[7];
    const float* bb2    = (const float*)d_in[8];
    const float* W_fo   = (const float*)d_in[9];
    const float* b_fo   = (const float*)d_in[10];
    const float* W_lat  = (const float*)d_in[11];
    const float* b_lat  = (const float*)d_in[12];
    const float* W_init = (const float*)d_in[13];
    const float* b_init = (const float*)d_in[14];
    const float* Wd1    = (const float*)d_in[15];
    const float* bd1    = (const float*)d_in[16];
    const float* Wd2    = (const float*)d_in[17];
    const float* bd2    = (const float*)d_in[18];
    const float* Wd3    = (const float*)d_in[19];
    const float* bd3    = (const float*)d_in[20];
    const float* Wg1    = (const float*)d_in[21];
    const float* bg1    = (const float*)d_in[22];
    const float* Wg2    = (const float*)d_in[23];
    const float* bg2    = (const float*)d_in[24];

    float* out   = (float*)d_out;
    float* mu_o  = out;                              // [NB,64]
    float* s_o   = out + (size_t)NB * 64;            // [NB,64]
    float* zpath = out + (size_t)2 * NB * 64;        // [64,NB,64]

    float* bufH = (float*)d_ws;                      // [NB,256]
    float* bufT = bufH + (size_t)NB * 256;           // [NB,256]
    // total ws use: 32 MB

    const dim3 blk(256);
    auto g = [&](const float* A, const float* W, const float* b,
                 const float* res, float* C, int N, int act) {
        dim3 grd(N / 64, NB / 128);
        gemm_bias_act<<<grd, blk, 0, stream>>>(A, W, b, res, C, NB, N, 256, act);
    };

    // encoder
    g(x, W_in, b_in, nullptr, bufH, 256, 1);                       // h = swish(x@W_in+b)
    for (int i = 0; i < 3; ++i) {
        g(bufH, Wb1 + (size_t)i * 65536, bb1 + i * 256, nullptr, bufT, 256, 1);
        g(bufT, Wb2 + (size_t)i * 65536, bb2 + i * 256, bufH, bufH, 256, 0);  // residual, in-place ok
    }
    g(bufH, W_fo, b_fo, nullptr, bufT, 256, 0);                    // features -> bufT
    g(bufT, W_lat, b_lat, nullptr, bufH, 128, 0);                  // latent_params -> bufH
    mu_s_kernel<<<dim3(NB * 64 / 256), blk, 0, stream>>>(bufH, mu_o, s_o);
    g(bufT, W_init, b_init, nullptr, zpath, 64, 0);                // z0 -> z_path[0]

    // SDE: 63 steps, persistent
    sde_kernel<<<dim3(NB / SROWS), blk, 0, stream>>>(
        ts, noise, Wd1, bd1, Wd2, bd2, Wd3, bd3, Wg1, bg1, Wg2, bg2, zpath);
}